// Round 1
// baseline (665.829 us; speedup 1.0000x reference)
//
#include <hip/hip_runtime.h>
#include <cstdint>
#include <cstddef>

// HetroGNN fused kernel: h = tanh(W_w @ concat(rel,ent) + b_w); s = u.h + b_u;
// att = softmax_n(mask ? -inf : s); out = tanh(sum_n att * ent).
// V2: software-pipelined. Batch b+1's raw data is prefetched into registers
// while batch b computes; cvt+LDS-write happens at the next loop top. Single
// LDS buffer (writes at loop top are WAR-safe: all MFMA reads of the previous
// batch completed before the post-MFMA barrier). 3 barriers/batch instead of 4.
// Numerics of the MFMA/softmax path identical to V1.

#define WAVES 4
#define BLOCK 256
#define NPAD 32
#define LDS_STRIDE 264  // 256 + 8 ushort pad: breaks LDS bank conflicts, keeps 16B align

typedef __attribute__((ext_vector_type(8))) short short8;
typedef __attribute__((ext_vector_type(4))) float f32x4;

__device__ __forceinline__ float fast_tanh(float x) {
  // tanh(x) = 1 - 2/(e^{2x}+1); exact saturation at +/-inf
  float e = __expf(2.0f * x);
  return 1.0f - 2.0f / (e + 1.0f);
}

__device__ __forceinline__ void cvt_hilo(float f, unsigned int& h, unsigned int& l) {
  unsigned int bits = __float_as_uint(f);
  h = bits >> 16;  // truncated bf16 hi
  float r = f - __uint_as_float(bits & 0xFFFF0000u);
  l = __float_as_uint(r) >> 16;  // bf16 of residual
}

__global__ __launch_bounds__(BLOCK, 2) void hetrognn_kernel(
    const float* __restrict__ rel, const float* __restrict__ ent,
    const int* __restrict__ mask, const float* __restrict__ Ww,
    const float* __restrict__ bw, const float* __restrict__ Wu,
    const float* __restrict__ bu, float* __restrict__ out, int Btot) {
  __shared__ unsigned short Ahi[NPAD * LDS_STRIDE];
  __shared__ unsigned short Alo[NPAD * LDS_STRIDE];
  __shared__ float pscore[WAVES][NPAD];
  __shared__ float att[NPAD];

  const int tid = threadIdx.x;
  const int wave = tid >> 6;
  const int lane = tid & 63;
  const int l15 = lane & 15;
  const int quad = lane >> 4;

  // ---- one-time: persistent W fragments (B-operand layout: n=lane&15, k=quad*8+j)
  short8 whi[2][8], wlo[2][8];
  float bwv[2], uv[2];
#pragma unroll
  for (int c = 0; c < 2; ++c) {
    const int d = wave * 32 + c * 16 + l15;
    bwv[c] = bw[d];
    uv[c] = Wu[d];
#pragma unroll
    for (int ks = 0; ks < 8; ++ks) {
      const float* wp = Ww + d * 256 + ks * 32 + quad * 8;
#pragma unroll
      for (int j = 0; j < 8; ++j) {
        unsigned int h, l;
        cvt_hilo(wp[j], h, l);
        whi[c][ks][j] = (short)h;
        wlo[c][ks][j] = (short)l;
      }
    }
  }
  const float buv = bu[0];

  // ---- pipeline prologue: load batch b0's raw data into registers ----
  float4 v[8];
  const int b0 = blockIdx.x;
  {
    const float* rb = rel + (size_t)b0 * 3840;
    const float* eb = ent + (size_t)b0 * 3840;
#pragma unroll
    for (int it = 0; it < 8; ++it) {
      const int i4 = tid + it * 256;
      const int row = i4 >> 6;
      const int k4 = (i4 & 63) << 2;
      v[it] = make_float4(0.f, 0.f, 0.f, 0.f);
      if (row < 30)
        v[it] = *(const float4*)((k4 < 128) ? (rb + row * 128 + k4)
                                            : (eb + row * 128 + (k4 - 128)));
    }
  }
  int mcur = 1;
  if (tid < 30) mcur = mask[(size_t)b0 * 30 + tid];

  for (int b = b0; b < Btot; b += gridDim.x) {
    // ---- stage regs -> LDS as bf16 hi/lo (rows 30/31 zero-pad) ----
    // WAR-safe without a barrier: all reads of Ahi/Alo for batch b-grid
    // completed before that iteration's post-MFMA __syncthreads().
#pragma unroll
    for (int it = 0; it < 8; ++it) {
      const int i4 = tid + it * 256;
      const int row = i4 >> 6;
      const int k4 = (i4 & 63) << 2;
      unsigned int h0, h1, h2, h3, l0, l1, l2, l3;
      cvt_hilo(v[it].x, h0, l0);
      cvt_hilo(v[it].y, h1, l1);
      cvt_hilo(v[it].z, h2, l2);
      cvt_hilo(v[it].w, h3, l3);
      uint2 hh, ll;
      hh.x = h0 | (h1 << 16);
      hh.y = h2 | (h3 << 16);
      ll.x = l0 | (l1 << 16);
      ll.y = l2 | (l3 << 16);
      *(uint2*)&Ahi[row * LDS_STRIDE + k4] = hh;
      *(uint2*)&Alo[row * LDS_STRIDE + k4] = ll;
    }

    // ---- prefetch batch b+grid into regs; latency hides under MFMA+softmax+out
    const int bn = b + (int)gridDim.x;
    int mnext = 1;
    if (bn < Btot) {
      const float* rb = rel + (size_t)bn * 3840;
      const float* eb = ent + (size_t)bn * 3840;
#pragma unroll
      for (int it = 0; it < 8; ++it) {
        const int i4 = tid + it * 256;
        const int row = i4 >> 6;
        const int k4 = (i4 & 63) << 2;
        if (row < 30)
          v[it] = *(const float4*)((k4 < 128) ? (rb + row * 128 + k4)
                                              : (eb + row * 128 + (k4 - 128)));
        else
          v[it] = make_float4(0.f, 0.f, 0.f, 0.f);
      }
      if (tid < 30) mnext = mask[(size_t)bn * 30 + tid];
    }
    __syncthreads();  // (1) staging visible to all waves

    // ---- MFMA: each wave computes 32 rows x its 32-col d-slice ----
#pragma unroll
    for (int mt = 0; mt < 2; ++mt) {
      f32x4 acc0 = {0.f, 0.f, 0.f, 0.f};
      f32x4 acc1 = {0.f, 0.f, 0.f, 0.f};
      const int arow = mt * 16 + l15;
      const unsigned short* abase = &Ahi[arow * LDS_STRIDE + quad * 8];
      const unsigned short* lbase = &Alo[arow * LDS_STRIDE + quad * 8];
#pragma unroll
      for (int ks = 0; ks < 8; ++ks) {
        short8 ah = *(const short8*)(abase + ks * 32);
        short8 al = *(const short8*)(lbase + ks * 32);
        acc0 = __builtin_amdgcn_mfma_f32_16x16x32_bf16(ah, whi[0][ks], acc0, 0, 0, 0);
        acc1 = __builtin_amdgcn_mfma_f32_16x16x32_bf16(ah, whi[1][ks], acc1, 0, 0, 0);
        acc0 = __builtin_amdgcn_mfma_f32_16x16x32_bf16(al, whi[0][ks], acc0, 0, 0, 0);
        acc1 = __builtin_amdgcn_mfma_f32_16x16x32_bf16(al, whi[1][ks], acc1, 0, 0, 0);
        acc0 = __builtin_amdgcn_mfma_f32_16x16x32_bf16(ah, wlo[0][ks], acc0, 0, 0, 0);
        acc1 = __builtin_amdgcn_mfma_f32_16x16x32_bf16(ah, wlo[1][ks], acc1, 0, 0, 0);
      }
      // epilogue: h = tanh(hpre + bw); partial score = sum_d u[d]*h over this wave's 32 d
      float part[4];
#pragma unroll
      for (int reg = 0; reg < 4; ++reg) {
        float h0 = fast_tanh(acc0[reg] + bwv[0]);
        float h1 = fast_tanh(acc1[reg] + bwv[1]);
        part[reg] = uv[0] * h0 + uv[1] * h1;
      }
      // butterfly-reduce across the 16 lanes of each quad (d dimension)
#pragma unroll
      for (int m = 1; m < 16; m <<= 1) {
#pragma unroll
        for (int reg = 0; reg < 4; ++reg) part[reg] += __shfl_xor(part[reg], m, 64);
      }
      float pv = (l15 == 0) ? part[0] : (l15 == 1) ? part[1] : (l15 == 2) ? part[2] : part[3];
      if (l15 < 4) pscore[wave][mt * 16 + quad * 4 + l15] = pv;
    }
    __syncthreads();  // (2) pscore visible

    // ---- softmax over n (wave0 lanes 0..31; mask came from prefetched reg) ----
    if (tid < 32) {
      const int n = tid;
      float raw = pscore[0][n] + pscore[1][n] + pscore[2][n] + pscore[3][n] + buv;
      const bool valid = (n < 30) && (mcur == 0);
      float sc = valid ? raw : -INFINITY;
      float mx = sc;
#pragma unroll
      for (int m = 1; m < 32; m <<= 1) mx = fmaxf(mx, __shfl_xor(mx, m, 64));
      float e = valid ? __expf(sc - mx) : 0.f;
      float sm = e;
#pragma unroll
      for (int m = 1; m < 32; m <<= 1) sm += __shfl_xor(sm, m, 64);
      att[n] = e / sm;
    }
    mcur = mnext;
    __syncthreads();  // (3) att visible

    // ---- output: out[b,d] = tanh(sum_n att[n] * ent[b,n,d]) ----
    // waves 2-3 skip this and run ahead into next batch's staging (no barrier
    // in between -> staging overlaps the output phase of waves 0-1).
    if (tid < 128) {
      const float* ep = ent + (size_t)b * 3840 + tid;
      float a0 = 0.f, a1 = 0.f;
#pragma unroll
      for (int n = 0; n < 30; n += 2) {
        a0 += att[n] * ep[n * 128];
        a1 += att[n + 1] * ep[(n + 1) * 128];
      }
      out[(size_t)b * 128 + tid] = fast_tanh(a0 + a1);
    }
  }
}

extern "C" void kernel_launch(void* const* d_in, const int* in_sizes, int n_in,
                              void* d_out, int out_size, void* d_ws, size_t ws_size,
                              hipStream_t stream) {
  const float* rel = (const float*)d_in[0];
  const float* ent = (const float*)d_in[1];
  const int* mask = (const int*)d_in[2];
  const float* Ww = (const float*)d_in[3];
  const float* bw = (const float*)d_in[4];
  const float* Wu = (const float*)d_in[5];
  const float* bu = (const float*)d_in[6];
  float* out = (float*)d_out;
  const int Btot = in_sizes[0] / 3840;  // B*N*D / (30*128)
  const int grid = 2048;
  hipLaunchKernelGGL(hetrognn_kernel, dim3(grid), dim3(BLOCK), 0, stream,
                     rel, ent, mask, Ww, bw, Wu, bu, out, Btot);
}

// Round 2
// 649.481 us; speedup vs baseline: 1.0252x; 1.0252x over previous
//
#include <hip/hip_runtime.h>
#include <cstdint>
#include <cstddef>

// HetroGNN fused kernel: h = tanh(W_w @ concat(rel,ent) + b_w); s = u.h + b_u;
// att = softmax_n(mask ? -inf : s); out = tanh(sum_n att * ent).
// V3: two batches per iteration (64 LDS rows = 4 MFMA row-tiles under the same
// persistent W registers) to halve per-batch barrier/softmax/output overhead;
// DPP-based 16-lane reduction (off the LDS pipe); no VGPR prefetch (V2's
// register prefetch spilled to scratch: W fragments = 128 AGPRs leave ~8 regs
// of headroom at 2 waves/EU).

#define WAVES 4
#define BLOCK 256
#define ROWS 64          // 2 batches x 32 rows (30 data + 2 zero-pad each)
#define LDS_STRIDE 264   // 256 + 8 ushort pad: breaks LDS bank conflicts, keeps 16B align

typedef __attribute__((ext_vector_type(8))) short short8;
typedef __attribute__((ext_vector_type(4))) float f32x4;

__device__ __forceinline__ float fast_tanh(float x) {
  // tanh(x) = 1 - 2/(e^{2x}+1); exact saturation at +/-inf
  float e = __expf(2.0f * x);
  return 1.0f - 2.0f / (e + 1.0f);
}

__device__ __forceinline__ void cvt_hilo(float f, unsigned int& h, unsigned int& l) {
  unsigned int bits = __float_as_uint(f);
  h = bits >> 16;  // truncated bf16 hi
  float r = f - __uint_as_float(bits & 0xFFFF0000u);
  l = __float_as_uint(r) >> 16;  // bf16 of residual
}

// one DPP cross-lane add step (VALU only, stays off the LDS pipe)
template <int CTRL>
__device__ __forceinline__ float dpp_add(float x) {
  return x + __int_as_float(
      __builtin_amdgcn_update_dpp(0, __float_as_int(x), CTRL, 0xF, 0xF, true));
}
// full sum across each 16-lane row: quad xor1, quad xor2, half-mirror, mirror
__device__ __forceinline__ float row16_sum(float x) {
  x = dpp_add<0xB1>(x);   // quad_perm(1,0,3,2)  : lane ^= 1
  x = dpp_add<0x4E>(x);   // quad_perm(2,3,0,1)  : lane ^= 2
  x = dpp_add<0x141>(x);  // row_half_mirror     : combine quads within 8
  x = dpp_add<0x140>(x);  // row_mirror          : combine 8-halves within 16
  return x;
}

__global__ __launch_bounds__(BLOCK, 2) void hetrognn_kernel(
    const float* __restrict__ rel, const float* __restrict__ ent,
    const int* __restrict__ mask, const float* __restrict__ Ww,
    const float* __restrict__ bw, const float* __restrict__ Wu,
    const float* __restrict__ bu, float* __restrict__ out, int Btot) {
  __shared__ unsigned short Ahi[ROWS * LDS_STRIDE];
  __shared__ unsigned short Alo[ROWS * LDS_STRIDE];
  __shared__ float pscore[WAVES][ROWS];
  __shared__ float att[ROWS];

  const int tid = threadIdx.x;
  const int wave = tid >> 6;
  const int lane = tid & 63;
  const int l15 = lane & 15;
  const int quad = lane >> 4;

  // ---- one-time: persistent W fragments (B-operand layout: n=lane&15, k=quad*8+j)
  short8 whi[2][8], wlo[2][8];
  float bwv[2], uv[2];
#pragma unroll
  for (int c = 0; c < 2; ++c) {
    const int d = wave * 32 + c * 16 + l15;
    bwv[c] = bw[d];
    uv[c] = Wu[d];
#pragma unroll
    for (int ks = 0; ks < 8; ++ks) {
      const float* wp = Ww + d * 256 + ks * 32 + quad * 8;
#pragma unroll
      for (int j = 0; j < 8; ++j) {
        unsigned int h, l;
        cvt_hilo(wp[j], h, l);
        whi[c][ks][j] = (short)h;
        wlo[c][ks][j] = (short)l;
      }
    }
  }
  const float buv = bu[0];

  const int pairs = (Btot + 1) >> 1;
  for (int p = blockIdx.x; p < pairs; p += gridDim.x) {
    const int bA = p * 2;
    const int bB = bA + 1;

    // ---- mask prefetch (wave 0 only; latency hides under staging+MFMA) ----
    int mreg = 1;
    if (tid < 64) {
      const int n = tid & 31;
      const int bb = bA + (tid >> 5);
      if (n < 30 && bb < Btot) mreg = mask[(size_t)bb * 30 + n];
    }

    // ---- stage both batches (32 rows each) as bf16 hi/lo; rows 30/31 zero ----
#pragma unroll
    for (int half = 0; half < 2; ++half) {
      const int bb = bA + half;
      const bool bvalid = (bb < Btot);
      const float* rb = rel + (size_t)bb * 3840;
      const float* eb = ent + (size_t)bb * 3840;
      const int rowbase = half * 32;
#pragma unroll
      for (int it = 0; it < 8; ++it) {
        const int i4 = tid + it * 256;  // float4 index 0..2047 within this batch
        const int row = i4 >> 6;        // 64 float4 per 256-wide row
        const int k4 = (i4 & 63) << 2;  // feature offset, multiple of 4
        float4 v = make_float4(0.f, 0.f, 0.f, 0.f);
        if (bvalid && row < 30) {
          const float* src = (k4 < 128) ? (rb + row * 128 + k4)
                                        : (eb + row * 128 + (k4 - 128));
          v = *(const float4*)src;
        }
        unsigned int h0, h1, h2, h3, l0, l1, l2, l3;
        cvt_hilo(v.x, h0, l0);
        cvt_hilo(v.y, h1, l1);
        cvt_hilo(v.z, h2, l2);
        cvt_hilo(v.w, h3, l3);
        uint2 hh, ll;
        hh.x = h0 | (h1 << 16);
        hh.y = h2 | (h3 << 16);
        ll.x = l0 | (l1 << 16);
        ll.y = l2 | (l3 << 16);
        *(uint2*)&Ahi[(rowbase + row) * LDS_STRIDE + k4] = hh;
        *(uint2*)&Alo[(rowbase + row) * LDS_STRIDE + k4] = ll;
      }
      // cap in-flight loads at 8 float4: do NOT let the compiler hoist the
      // second batch's loads above the first batch's converts (V2 spilled).
      asm volatile("" ::: "memory");
    }
    __syncthreads();  // (1) staging visible

    // ---- MFMA: each wave computes 64 rows x its 32-col d-slice (4 tiles) ----
#pragma unroll
    for (int mt = 0; mt < 4; ++mt) {
      f32x4 acc0 = {0.f, 0.f, 0.f, 0.f};
      f32x4 acc1 = {0.f, 0.f, 0.f, 0.f};
      const int arow = mt * 16 + l15;
      const unsigned short* abase = &Ahi[arow * LDS_STRIDE + quad * 8];
      const unsigned short* lbase = &Alo[arow * LDS_STRIDE + quad * 8];
#pragma unroll
      for (int ks = 0; ks < 8; ++ks) {
        short8 ah = *(const short8*)(abase + ks * 32);
        short8 al = *(const short8*)(lbase + ks * 32);
        acc0 = __builtin_amdgcn_mfma_f32_16x16x32_bf16(ah, whi[0][ks], acc0, 0, 0, 0);
        acc1 = __builtin_amdgcn_mfma_f32_16x16x32_bf16(ah, whi[1][ks], acc1, 0, 0, 0);
        acc0 = __builtin_amdgcn_mfma_f32_16x16x32_bf16(al, whi[0][ks], acc0, 0, 0, 0);
        acc1 = __builtin_amdgcn_mfma_f32_16x16x32_bf16(al, whi[1][ks], acc1, 0, 0, 0);
        acc0 = __builtin_amdgcn_mfma_f32_16x16x32_bf16(ah, wlo[0][ks], acc0, 0, 0, 0);
        acc1 = __builtin_amdgcn_mfma_f32_16x16x32_bf16(ah, wlo[1][ks], acc1, 0, 0, 0);
      }
      // epilogue: h = tanh(hpre + bw); partial score = sum_d u[d]*h over this wave's 32 d
      float part[4];
#pragma unroll
      for (int reg = 0; reg < 4; ++reg) {
        float h0 = fast_tanh(acc0[reg] + bwv[0]);
        float h1 = fast_tanh(acc1[reg] + bwv[1]);
        part[reg] = uv[0] * h0 + uv[1] * h1;
      }
      // DPP reduce across the 16 lanes of each quad (d dimension) — VALU only
#pragma unroll
      for (int reg = 0; reg < 4; ++reg) part[reg] = row16_sum(part[reg]);
      float pv = (l15 == 0) ? part[0] : (l15 == 1) ? part[1] : (l15 == 2) ? part[2] : part[3];
      if (l15 < 4) pscore[wave][mt * 16 + quad * 4 + l15] = pv;
    }
    __syncthreads();  // (2) pscore visible

    // ---- softmax: wave 0, lanes 0-31 = batch A, lanes 32-63 = batch B ----
    if (tid < 64) {
      const int n = tid & 31;
      const int base = tid & 32;  // 0 or 32
      float raw = pscore[0][base + n] + pscore[1][base + n] +
                  pscore[2][base + n] + pscore[3][base + n] + buv;
      const bool valid = (n < 30) && (mreg == 0);
      float sc = valid ? raw : -INFINITY;
      float mx = sc;
#pragma unroll
      for (int m = 1; m < 32; m <<= 1) mx = fmaxf(mx, __shfl_xor(mx, m, 32));
      float e = valid ? __expf(sc - mx) : 0.f;
      float sm = e;
#pragma unroll
      for (int m = 1; m < 32; m <<= 1) sm += __shfl_xor(sm, m, 32);
      att[base + n] = e / sm;
    }
    __syncthreads();  // (3) att visible

    // ---- output: all 256 threads; tid<128 -> batch A, tid>=128 -> batch B ----
    {
      const int half = tid >> 7;
      const int d = tid & 127;
      const int bb = bA + half;
      if (bb < Btot) {
        const float* ep = ent + (size_t)bb * 3840 + d;  // L2-hot: staged this iter
        const float* ap = &att[half * 32];
        float a0 = 0.f, a1 = 0.f;
#pragma unroll
        for (int n = 0; n < 30; n += 2) {
          a0 += ap[n] * ep[n * 128];
          a1 += ap[n + 1] * ep[(n + 1) * 128];
        }
        out[(size_t)bb * 128 + d] = fast_tanh(a0 + a1);
      }
    }
    __syncthreads();  // (4) protect LDS (att + Ahi/Alo) before next staging
  }
}

extern "C" void kernel_launch(void* const* d_in, const int* in_sizes, int n_in,
                              void* d_out, int out_size, void* d_ws, size_t ws_size,
                              hipStream_t stream) {
  const float* rel = (const float*)d_in[0];
  const float* ent = (const float*)d_in[1];
  const int* mask = (const int*)d_in[2];
  const float* Ww = (const float*)d_in[3];
  const float* bw = (const float*)d_in[4];
  const float* Wu = (const float*)d_in[5];
  const float* bu = (const float*)d_in[6];
  float* out = (float*)d_out;
  const int Btot = in_sizes[0] / 3840;  // B*N*D / (30*128)
  const int grid = 2048;
  hipLaunchKernelGGL(hetrognn_kernel, dim3(grid), dim3(BLOCK), 0, stream,
                     rel, ent, mask, Ww, bw, Wu, bu, out, Btot);
}

// Round 3
// 600.400 us; speedup vs baseline: 1.1090x; 1.0817x over previous
//
#include <hip/hip_runtime.h>
#include <cstdint>
#include <cstddef>

// HetroGNN fused kernel: h = tanh(W_w @ concat(rel,ent) + b_w); s = u.h + b_u;
// att = softmax_n(mask ? -inf : s); out = tanh(sum_n att * ent).
// V4: occupancy attack. 512-thread blocks, 8 waves, each wave owns 16 d-columns
// -> W hi/lo fragments = 64 regs/wave (was 128). __launch_bounds__(512,4) caps
// total regs at 128/wave -> 16 waves/CU (2x V1-V3's 8). Two batches per
// iteration; per-tile epilogue keeps one f32x4 accumulator live; staging holds
// only 4 float4 in flight per half. MFMA numeric chain identical to V1-V3.

#define WAVES 8
#define BLOCK 512
#define ROWS 64          // 2 batches x 32 rows (30 data + 2 zero-pad each)
#define LDS_STRIDE 264   // 256 + 8 ushort pad: breaks LDS bank conflicts, keeps 16B align

typedef __attribute__((ext_vector_type(8))) short short8;
typedef __attribute__((ext_vector_type(4))) float f32x4;

__device__ __forceinline__ float fast_tanh(float x) {
  // tanh(x) = 1 - 2/(e^{2x}+1); exact saturation at +/-inf
  float e = __expf(2.0f * x);
  return 1.0f - 2.0f / (e + 1.0f);
}

__device__ __forceinline__ void cvt_hilo(float f, unsigned int& h, unsigned int& l) {
  unsigned int bits = __float_as_uint(f);
  h = bits >> 16;  // truncated bf16 hi
  float r = f - __uint_as_float(bits & 0xFFFF0000u);
  l = __float_as_uint(r) >> 16;  // bf16 of residual
}

// one DPP cross-lane add step (VALU only, stays off the LDS pipe)
template <int CTRL>
__device__ __forceinline__ float dpp_add(float x) {
  return x + __int_as_float(
      __builtin_amdgcn_update_dpp(0, __float_as_int(x), CTRL, 0xF, 0xF, true));
}
// full sum across each 16-lane row: quad xor1, quad xor2, half-mirror, mirror
__device__ __forceinline__ float row16_sum(float x) {
  x = dpp_add<0xB1>(x);   // quad_perm(1,0,3,2)  : lane ^= 1
  x = dpp_add<0x4E>(x);   // quad_perm(2,3,0,1)  : lane ^= 2
  x = dpp_add<0x141>(x);  // row_half_mirror     : combine quads within 8
  x = dpp_add<0x140>(x);  // row_mirror          : combine 8-halves within 16
  return x;
}

__global__ __launch_bounds__(BLOCK, 4) void hetrognn_kernel(
    const float* __restrict__ rel, const float* __restrict__ ent,
    const int* __restrict__ mask, const float* __restrict__ Ww,
    const float* __restrict__ bw, const float* __restrict__ Wu,
    const float* __restrict__ bu, float* __restrict__ out, int Btot) {
  __shared__ unsigned short Ahi[ROWS * LDS_STRIDE];
  __shared__ unsigned short Alo[ROWS * LDS_STRIDE];
  __shared__ float pscore[WAVES][ROWS];
  __shared__ float att[ROWS];

  const int tid = threadIdx.x;
  const int wave = tid >> 6;   // 0..7
  const int lane = tid & 63;
  const int l15 = lane & 15;
  const int quad = lane >> 4;

  // ---- one-time: persistent W fragments, 16 d-columns per wave ----
  // B-operand layout: col(d) = lane&15, k = quad*8 + j. 64 regs/wave hi+lo.
  short8 whi[8], wlo[8];
  const int d = wave * 16 + l15;
  const float bwv = bw[d];
  const float uv = Wu[d];
#pragma unroll
  for (int ks = 0; ks < 8; ++ks) {
    const float* wp = Ww + d * 256 + ks * 32 + quad * 8;
#pragma unroll
    for (int j = 0; j < 8; ++j) {
      unsigned int h, l;
      cvt_hilo(wp[j], h, l);
      whi[ks][j] = (short)h;
      wlo[ks][j] = (short)l;
    }
  }
  const float buv = bu[0];

  const int pairs = (Btot + 1) >> 1;
  for (int p = blockIdx.x; p < pairs; p += gridDim.x) {
    const int bA = p * 2;

    // ---- mask prefetch (wave 0; latency hides under staging+MFMA) ----
    int mreg = 1;
    if (tid < 64) {
      const int n = tid & 31;
      const int bb = bA + (tid >> 5);
      if (n < 30 && bb < Btot) mreg = mask[(size_t)bb * 30 + n];
    }

    // ---- stage both batches (32 rows each) as bf16 hi/lo; rows 30/31 zero ----
    // 512 threads -> 4 float4 per thread per batch (16 regs in flight max).
#pragma unroll
    for (int half = 0; half < 2; ++half) {
      const int bb = bA + half;
      const bool bvalid = (bb < Btot);
      const float* rb = rel + (size_t)bb * 3840;
      const float* eb = ent + (size_t)bb * 3840;
      const int rowbase = half * 32;
#pragma unroll
      for (int it = 0; it < 4; ++it) {
        const int i4 = tid + it * 512;  // float4 index 0..2047 within this batch
        const int row = i4 >> 6;        // 64 float4 per 256-wide row
        const int k4 = (i4 & 63) << 2;  // feature offset, multiple of 4
        float4 v = make_float4(0.f, 0.f, 0.f, 0.f);
        if (bvalid && row < 30) {
          const float* src = (k4 < 128) ? (rb + row * 128 + k4)
                                        : (eb + row * 128 + (k4 - 128));
          v = *(const float4*)src;
        }
        unsigned int h0, h1, h2, h3, l0, l1, l2, l3;
        cvt_hilo(v.x, h0, l0);
        cvt_hilo(v.y, h1, l1);
        cvt_hilo(v.z, h2, l2);
        cvt_hilo(v.w, h3, l3);
        uint2 hh, ll;
        hh.x = h0 | (h1 << 16);
        hh.y = h2 | (h3 << 16);
        ll.x = l0 | (l1 << 16);
        ll.y = l2 | (l3 << 16);
        *(uint2*)&Ahi[(rowbase + row) * LDS_STRIDE + k4] = hh;
        *(uint2*)&Alo[(rowbase + row) * LDS_STRIDE + k4] = ll;
      }
      // keep in-flight loads capped (register headroom is ~64 non-W regs)
      asm volatile("" ::: "memory");
    }
    __syncthreads();  // (1) staging visible

    // ---- MFMA: each wave computes 64 rows x its 16-col d-slice (4 tiles) ----
#pragma unroll
    for (int mt = 0; mt < 4; ++mt) {
      f32x4 acc = {0.f, 0.f, 0.f, 0.f};
      const int arow = mt * 16 + l15;
      const unsigned short* abase = &Ahi[arow * LDS_STRIDE + quad * 8];
      const unsigned short* lbase = &Alo[arow * LDS_STRIDE + quad * 8];
#pragma unroll
      for (int ks = 0; ks < 8; ++ks) {
        short8 ah = *(const short8*)(abase + ks * 32);
        short8 al = *(const short8*)(lbase + ks * 32);
        acc = __builtin_amdgcn_mfma_f32_16x16x32_bf16(ah, whi[ks], acc, 0, 0, 0);
        acc = __builtin_amdgcn_mfma_f32_16x16x32_bf16(al, whi[ks], acc, 0, 0, 0);
        acc = __builtin_amdgcn_mfma_f32_16x16x32_bf16(ah, wlo[ks], acc, 0, 0, 0);
      }
      // epilogue: h = tanh(hpre + bw); partial score = sum over this wave's 16 d
      float part[4];
#pragma unroll
      for (int reg = 0; reg < 4; ++reg) part[reg] = uv * fast_tanh(acc[reg] + bwv);
      // DPP reduce across the 16 lanes (d dimension) — VALU only
#pragma unroll
      for (int reg = 0; reg < 4; ++reg) part[reg] = row16_sum(part[reg]);
      float pv = (l15 == 0) ? part[0] : (l15 == 1) ? part[1] : (l15 == 2) ? part[2] : part[3];
      if (l15 < 4) pscore[wave][mt * 16 + quad * 4 + l15] = pv;
    }
    __syncthreads();  // (2) pscore visible

    // ---- softmax: wave 0, lanes 0-31 = batch A, lanes 32-63 = batch B ----
    if (tid < 64) {
      const int n = tid & 31;
      const int base = tid & 32;  // 0 or 32
      float raw = buv;
#pragma unroll
      for (int w = 0; w < WAVES; ++w) raw += pscore[w][base + n];
      const bool valid = (n < 30) && (mreg == 0);
      float sc = valid ? raw : -INFINITY;
      float mx = sc;
#pragma unroll
      for (int m = 1; m < 32; m <<= 1) mx = fmaxf(mx, __shfl_xor(mx, m, 32));
      float e = valid ? __expf(sc - mx) : 0.f;
      float sm = e;
#pragma unroll
      for (int m = 1; m < 32; m <<= 1) sm += __shfl_xor(sm, m, 32);
      att[base + n] = e / sm;
    }
    __syncthreads();  // (3) att visible

    // ---- output: threads 0-255; tid<128 -> batch A, else batch B ----
    if (tid < 256) {
      const int half = tid >> 7;
      const int dd = tid & 127;
      const int bb = bA + half;
      if (bb < Btot) {
        const float* ep = ent + (size_t)bb * 3840 + dd;  // L2-hot: staged this iter
        const float* ap = &att[half * 32];
        float a0 = 0.f, a1 = 0.f;
#pragma unroll
        for (int n = 0; n < 30; n += 2) {
          a0 += ap[n] * ep[n * 128];
          a1 += ap[n + 1] * ep[(n + 1) * 128];
        }
        out[(size_t)bb * 128 + dd] = fast_tanh(a0 + a1);
      }
    }
    __syncthreads();  // (4) protect LDS (att + Ahi/Alo) before next staging
  }
}

extern "C" void kernel_launch(void* const* d_in, const int* in_sizes, int n_in,
                              void* d_out, int out_size, void* d_ws, size_t ws_size,
                              hipStream_t stream) {
  const float* rel = (const float*)d_in[0];
  const float* ent = (const float*)d_in[1];
  const int* mask = (const int*)d_in[2];
  const float* Ww = (const float*)d_in[3];
  const float* bw = (const float*)d_in[4];
  const float* Wu = (const float*)d_in[5];
  const float* bu = (const float*)d_in[6];
  float* out = (float*)d_out;
  const int Btot = in_sizes[0] / 3840;  // B*N*D / (30*128)
  const int grid = 2048;
  hipLaunchKernelGGL(hetrognn_kernel, dim3(grid), dim3(BLOCK), 0, stream,
                     rel, ent, mask, Ww, bw, Wu, bu, out, Btot);
}